// Round 9
// baseline (383.885 us; speedup 1.0000x reference)
//
#include <hip/hip_runtime.h>
#include <hip/hip_bf16.h>

// SplineCNN round 24: r23 banked (380.5us; edge dropped below gemm in top-5).
// Two additive tweaks:
//  (a) edge_csr: 2 dsts per wave, independent 4-edge quad streams -> up to
//      64 gathers in flight/wave (was 32). VGPR ~120 caps occ ~16 waves/CU
//      but net in-flight/CU +50%. Predicted edge ~67 -> 58-62us.
//  (b) deg zeroed via hipMemsetAsync; hist_deg FUSED into prep tail region
//      (800k atomics overlap prep's 23MB stream; one fewer launch+drain).
// gemm_scatter / scans / final verbatim r23.

typedef short  bf16x8 __attribute__((ext_vector_type(8)));
typedef float  f32x4  __attribute__((ext_vector_type(4)));
typedef int    i32x4  __attribute__((ext_vector_type(4)));
typedef ushort u16x8  __attribute__((ext_vector_type(8)));

__device__ __forceinline__ float bf2f(ushort u) {
    return __uint_as_float((uint)u << 16);
}
__device__ __forceinline__ ushort f2bf(float f) {   // round-to-nearest-even
    uint u = __float_as_uint(f);
    return (ushort)((u + 0x7FFF + ((u >> 16) & 1)) >> 16);
}

// ---------------- fused prep (+ hist) -----------------------------------
// [0, nx8): xb = bf16(x), 8 elems/thread
// [+nw): WtA ; [+nw): WtB ; [+nfw): fwT ; [+E): deg histogram (deg pre-zeroed)
__global__ __launch_bounds__(256) void prep(
    const float* __restrict__ x, ushort* __restrict__ xb, int nx8,
    const float* __restrict__ W1, const float* __restrict__ r1, ushort* __restrict__ WtA,
    const float* __restrict__ W2, const float* __restrict__ r2, ushort* __restrict__ WtB,
    const float* __restrict__ fw, ushort* __restrict__ fwT,
    const int* __restrict__ ei, int* __restrict__ deg, int E)
{
    const int nw = 26 * 4096, nfw = 3 * 4096;
    int idx = blockIdx.x * 256 + threadIdx.x;
    if (idx < nx8) {
        float4 v0 = *(const float4*)(x + (size_t)idx * 8);
        float4 v1 = *(const float4*)(x + (size_t)idx * 8 + 4);
        u16x8 o;
        o[0] = f2bf(v0.x); o[1] = f2bf(v0.y); o[2] = f2bf(v0.z); o[3] = f2bf(v0.w);
        o[4] = f2bf(v1.x); o[5] = f2bf(v1.y); o[6] = f2bf(v1.z); o[7] = f2bf(v1.w);
        *(u16x8*)(xb + (size_t)idx * 8) = o;
        return;
    }
    idx -= nx8;
    if (idx < nw) {
        int tile = idx >> 12, rem = idx & 4095, o = rem >> 6, i = rem & 63;
        WtA[idx] = f2bf(tile < 25 ? W1[tile * 4096 + i * 64 + o] : r1[i * 64 + o]);
        return;
    }
    idx -= nw;
    if (idx < nw) {
        int tile = idx >> 12, rem = idx & 4095, o = rem >> 6, i = rem & 63;
        WtB[idx] = f2bf(tile < 25 ? W2[tile * 4096 + i * 64 + o] : r2[i * 64 + o]);
        return;
    }
    idx -= nw;
    if (idx < nfw) {
        int t = idx >> 12, rem = idx & 4095, o = rem >> 6, k = rem & 63;
        fwT[idx] = f2bf(fw[(t * 64 + k) * 64 + o]);
        return;
    }
    idx -= nfw;
    if (idx < E) atomicAdd(&deg[ei[E + idx]], 1);
}

// ---------------- CSR scan chain ----------------------------------------
__global__ __launch_bounds__(1024) void scan_block(
    const int* __restrict__ deg, int* __restrict__ inc,
    int* __restrict__ partial, int N)
{
    __shared__ int s[1024];
    int i = blockIdx.x * 1024 + threadIdx.x;
    int v = (i < N) ? deg[i] : 0;
    s[threadIdx.x] = v;
    __syncthreads();
    for (int off = 1; off < 1024; off <<= 1) {
        int t = (threadIdx.x >= off) ? s[threadIdx.x - off] : 0;
        __syncthreads();
        s[threadIdx.x] += t;
        __syncthreads();
    }
    if (i < N) inc[i] = s[threadIdx.x];
    if (threadIdx.x == 1023) partial[blockIdx.x] = s[1023];
}

__global__ void scan_partial(int* __restrict__ partial, int nb)  // nb <= 64
{
    __shared__ int s[64];
    int t = threadIdx.x;
    int v = (t < nb) ? partial[t] : 0;
    s[t] = v;
    __syncthreads();
    for (int off = 1; off < 64; off <<= 1) {
        int x = (t >= off) ? s[t - off] : 0;
        __syncthreads();
        s[t] += x;
        __syncthreads();
    }
    if (t < nb) partial[t] = s[t] - v;   // exclusive block offsets
}

__global__ __launch_bounds__(1024) void scan_finalize(
    const int* __restrict__ deg, const int* __restrict__ inc,
    const int* __restrict__ partial, int* __restrict__ row_ptr,
    int* __restrict__ cursor, int N)
{
    int i = blockIdx.x * 1024 + threadIdx.x;
    if (i >= N) return;
    int v = inc[i] + partial[blockIdx.x];
    row_ptr[i + 1] = v;
    cursor[i] = v - deg[i];
    if (i == 0) row_ptr[0] = 0;
}

// ---------------- fused MFMA GEMM + csr_scatter (barrier-free) ----------
__global__ __launch_bounds__(256) void gemm_scatter(
    const ushort* __restrict__ A, const ushort* __restrict__ Wt,
    ushort* __restrict__ xWb, ushort* __restrict__ xRoot, int mtiles,
    const int* __restrict__ ei, const float* __restrict__ attr,
    int* __restrict__ cursor, int4* __restrict__ epack, int E)
{
    __shared__ ushort Cs[4][16][72];   // per-wave slice, 144B rows
    const int bx = blockIdx.x;

    if (bx >= 26) {                 // ---- scatter path (layer 1 only) ----
        if (!ei) return;
        int e = ((bx - 26) * gridDim.y + blockIdx.y) * 256 + threadIdx.x;
        if (e >= E) return;
        int src = ei[e], dst = ei[E + e];
        float u = attr[2 * e] * 4.f;
        float v = attr[2 * e + 1] * 4.f;
        float lu = floorf(u), lv = floorf(v);
        float fu = u - lu, fv = v - lv;
        int iu = (int)lu;  iu = iu < 0 ? 0 : (iu > 4 ? 4 : iu);
        int iv = (int)lv;  iv = iv < 0 ? 0 : (iv > 4 ? 4 : iv);
        int iu1 = iu + 1 > 4 ? 4 : iu + 1;
        int iv1 = iv + 1 > 4 ? 4 : iv + 1;
        uint slots = (uint)(iu + 5 * iv) | ((uint)(iu + 5 * iv1) << 8) |
                     ((uint)(iu1 + 5 * iv) << 16) | ((uint)(iu1 + 5 * iv1) << 24);
        uint wlo = (uint)f2bf((1.f - fu) * (1.f - fv)) | ((uint)f2bf((1.f - fu) * fv) << 16);
        uint whi = (uint)f2bf(fu * (1.f - fv)) | ((uint)f2bf(fu * fv) << 16);
        int pos = atomicAdd(&cursor[dst], 1);
        i32x4 pk = {src * 3200, (int)slots, (int)wlo, (int)whi};
        __builtin_nontemporal_store(pk, (i32x4*)(epack + pos));   // nt: no write-allocate RMW
        return;
    }

    // ---- gemm path ----
    const int wave = threadIdx.x >> 6;
    const int lane = threadIdx.x & 63;
    const int l16 = lane & 15;
    const int half = lane >> 4;                 // 0..3
    ushort (*cw)[72] = Cs[wave];

    const ushort* btile = Wt + (size_t)bx * 4096;
    bf16x8 b0[4], b1[4];
    #pragma unroll
    for (int s = 0; s < 4; ++s) {
        const ushort* brow = btile + (size_t)(s * 16 + l16) * 64;
        b0[s] = *(const bf16x8*)(brow + half * 8);
        b1[s] = *(const bf16x8*)(brow + 32 + half * 8);
    }

    const int mt_base = blockIdx.y * 8;
    const int nit = (mtiles - mt_base) < 8 ? (mtiles - mt_base) : 8;

    // prefetch A for it=0
    const ushort* arow0 = A + (size_t)(mt_base * 64 + wave * 16 + l16) * 64;
    bf16x8 a0 = *(const bf16x8*)(arow0 + half * 8);
    bf16x8 a1 = *(const bf16x8*)(arow0 + 32 + half * 8);

    for (int it = 0; it < nit; ++it) {
        const int m0 = (mt_base + it) * 64;
        const int m_base = m0 + wave * 16;

        // issue next iteration's A loads BEFORE this iteration's stores
        bf16x8 na0, na1;
        if (it + 1 < nit) {
            const ushort* arow = A + (size_t)(m_base + 64 + l16) * 64;
            na0 = *(const bf16x8*)(arow + half * 8);
            na1 = *(const bf16x8*)(arow + 32 + half * 8);
        }

        f32x4 acc[4];
        #pragma unroll
        for (int s = 0; s < 4; ++s) {
            acc[s] = (f32x4){0.f, 0.f, 0.f, 0.f};
            acc[s] = __builtin_amdgcn_mfma_f32_16x16x32_bf16(a0, b0[s], acc[s], 0, 0, 0);
            acc[s] = __builtin_amdgcn_mfma_f32_16x16x32_bf16(a1, b1[s], acc[s], 0, 0, 0);
        }

        if (bx == 25) {   // root tile -> bf16 xRoot (padded ws, no guard)
            #pragma unroll
            for (int s = 0; s < 4; ++s)
                #pragma unroll
                for (int r = 0; r < 4; ++r)
                    xRoot[(size_t)(m_base + half * 4 + r) * 64 + s * 16 + l16] = f2bf(acc[s][r]);
        } else {
            // per-wave stage: bf16 fragment -> LDS slice (same-wave only)
            #pragma unroll
            for (int s = 0; s < 4; ++s)
                #pragma unroll
                for (int r = 0; r < 4; ++r)
                    cw[half * 4 + r][s * 16 + l16] = f2bf(acc[s][r]);
            // same-wave readback -> coalesced uint4 stores of our 16 rows
            #pragma unroll
            for (int i2 = 0; i2 < 2; ++i2) {
                int idx = i2 * 64 + lane;
                int row = idx >> 3, seg = idx & 7;
                uint4 v = *(const uint4*)&cw[row][seg * 8];
                *(uint4*)(xWb + (size_t)(m_base + row) * 1600 + bx * 64 + seg * 8) = v;
            }
        }
        a0 = na0; a1 = na1;
    }
}

// ---------------- edge pass: 2 dsts/wave, dual 4-edge quad streams ------
__device__ __forceinline__ void gather4(
    const char* __restrict__ xwb, int lane, int rb, uint slots, ushort g[4])
{
    g[0] = *((const ushort*)(xwb + rb + ((slots & 255u) << 7)) + lane);
    g[1] = *((const ushort*)(xwb + rb + (((slots >> 8) & 255u) << 7)) + lane);
    g[2] = *((const ushort*)(xwb + rb + (((slots >> 16) & 255u) << 7)) + lane);
    g[3] = *((const ushort*)(xwb + rb + ((slots >> 24) << 7)) + lane);
}

__device__ __forceinline__ float consume4(const int4 d, const ushort g[4])
{
    float m = __uint_as_float((uint)d.z << 16) * bf2f(g[0]);
    m = fmaf(__uint_as_float((uint)d.z & 0xffff0000u), bf2f(g[1]), m);
    m = fmaf(__uint_as_float((uint)d.w << 16), bf2f(g[2]), m);
    m = fmaf(__uint_as_float((uint)d.w & 0xffff0000u), bf2f(g[3]), m);
    return m;
}

__global__ __launch_bounds__(256) void edge_csr(
    const ushort* __restrict__ xWb, const int* __restrict__ row_ptr,
    const int4* __restrict__ epack, const ushort* __restrict__ xRoot,
    const float* __restrict__ bias, ushort* __restrict__ outb, int N)
{
    const int wv = __builtin_amdgcn_readfirstlane(threadIdx.x >> 6);
    const int lane = threadIdx.x & 63;
    const int dA = blockIdx.x * 8 + wv * 2;
    if (dA >= N) return;
    const int dB = dA + 1;
    const bool hasB = dB < N;
    const char* xwb = (const char*)xWb;

    const int a0 = __builtin_amdgcn_readfirstlane(row_ptr[dA]);
    const int a1 = __builtin_amdgcn_readfirstlane(row_ptr[dA + 1]);
    const int b0 = hasB ? __builtin_amdgcn_readfirstlane(row_ptr[dB]) : 0;
    const int b1 = hasB ? __builtin_amdgcn_readfirstlane(row_ptr[dB + 1]) : 0;
    const int cntA = a1 - a0, cntB = b1 - b0;
    const int qA = cntA >> 2, qB = cntB >> 2;
    const int qmax = qA > qB ? qA : qB;

    float vmA = -__builtin_inff(), vmB = -__builtin_inff();
    int4 dqA[4], dqB[4];
    ushort gqA[4][4], gqB[4][4];

    if (qA > 0) {
        #pragma unroll
        for (int j = 0; j < 4; ++j) {
            dqA[j] = epack[a0 + j];
            gather4(xwb, lane, dqA[j].x, (uint)dqA[j].y, gqA[j]);
        }
    }
    if (qB > 0) {
        #pragma unroll
        for (int j = 0; j < 4; ++j) {
            dqB[j] = epack[b0 + j];
            gather4(xwb, lane, dqB[j].x, (uint)dqB[j].y, gqB[j]);
        }
    }

    for (int q = 0; q < qmax; ++q) {
        int4 ndA[4], ndB[4];
        ushort ngA[4][4], ngB[4][4];
        const bool pA = (q + 1 < qA), pB = (q + 1 < qB);
        if (pA) {
            #pragma unroll
            for (int j = 0; j < 4; ++j) {
                ndA[j] = epack[a0 + 4 * (q + 1) + j];
                gather4(xwb, lane, ndA[j].x, (uint)ndA[j].y, ngA[j]);
            }
        }
        if (pB) {
            #pragma unroll
            for (int j = 0; j < 4; ++j) {
                ndB[j] = epack[b0 + 4 * (q + 1) + j];
                gather4(xwb, lane, ndB[j].x, (uint)ndB[j].y, ngB[j]);
            }
        }
        if (q < qA) {
            #pragma unroll
            for (int j = 0; j < 4; ++j) vmA = fmaxf(vmA, consume4(dqA[j], gqA[j]));
        }
        if (q < qB) {
            #pragma unroll
            for (int j = 0; j < 4; ++j) vmB = fmaxf(vmB, consume4(dqB[j], gqB[j]));
        }
        if (pA) {
            #pragma unroll
            for (int j = 0; j < 4; ++j) {
                dqA[j] = ndA[j];
                #pragma unroll
                for (int i = 0; i < 4; ++i) gqA[j][i] = ngA[j][i];
            }
        }
        if (pB) {
            #pragma unroll
            for (int j = 0; j < 4; ++j) {
                dqB[j] = ndB[j];
                #pragma unroll
                for (int i = 0; i < 4; ++i) gqB[j][i] = ngB[j][i];
            }
        }
    }

    for (int e = a0 + qA * 4; e < a1; ++e) {   // A remainder (<=3)
        int4 d = epack[e];
        ushort g[4];
        gather4(xwb, lane, d.x, (uint)d.y, g);
        vmA = fmaxf(vmA, consume4(d, g));
    }
    for (int e = b0 + qB * 4; e < b1; ++e) {   // B remainder (<=3)
        int4 d = epack[e];
        ushort g[4];
        gather4(xwb, lane, d.x, (uint)d.y, g);
        vmB = fmaxf(vmB, consume4(d, g));
    }

    if (cntA == 0) vmA = 0.f;
    float valA = vmA + bf2f(xRoot[(size_t)dA * 64 + lane]) + bias[lane];
    outb[(size_t)dA * 64 + lane] = f2bf(fmaxf(valA, 0.f));
    if (hasB) {
        if (cntB == 0) vmB = 0.f;
        float valB = vmB + bf2f(xRoot[(size_t)dB * 64 + lane]) + bias[lane];
        outb[(size_t)dB * 64 + lane] = f2bf(fmaxf(valB, 0.f));
    }
}

// ---------------- final: out = [xb|x1b|x2b] @ fwT + fb (bf16 MFMA) ------
__global__ __launch_bounds__(256) void final_mfma(
    const ushort* __restrict__ xb, const ushort* __restrict__ x1b,
    const ushort* __restrict__ x2b, const ushort* __restrict__ fwT,
    const float* __restrict__ fb, float* __restrict__ out, int M)
{
    const int wave = threadIdx.x >> 6;
    const int lane = threadIdx.x & 63;
    const int l16 = lane & 15;
    const int half = lane >> 4;
    const int m_base = blockIdx.x * 64 + wave * 16;
    const ushort* srcs[3] = {xb, x1b, x2b};

    f32x4 acc[4];
    #pragma unroll
    for (int s = 0; s < 4; ++s) acc[s] = (f32x4){0.f, 0.f, 0.f, 0.f};

    #pragma unroll
    for (int t = 0; t < 3; ++t) {
        const ushort* arow = srcs[t] + (size_t)(m_base + l16) * 64;
        bf16x8 a0 = *(const bf16x8*)(arow + half * 8);
        bf16x8 a1 = *(const bf16x8*)(arow + 32 + half * 8);
        const ushort* btile = fwT + (size_t)t * 4096;
        #pragma unroll
        for (int s = 0; s < 4; ++s) {
            const ushort* brow = btile + (size_t)(s * 16 + l16) * 64;
            bf16x8 b0 = *(const bf16x8*)(brow + half * 8);
            bf16x8 b1 = *(const bf16x8*)(brow + 32 + half * 8);
            acc[s] = __builtin_amdgcn_mfma_f32_16x16x32_bf16(a0, b0, acc[s], 0, 0, 0);
            acc[s] = __builtin_amdgcn_mfma_f32_16x16x32_bf16(a1, b1, acc[s], 0, 0, 0);
        }
    }

    #pragma unroll
    for (int s = 0; s < 4; ++s) {
        int o = s * 16 + l16;
        float b = fb[o];
        #pragma unroll
        for (int r = 0; r < 4; ++r) {
            int m = m_base + half * 4 + r;
            if (m < M) out[(size_t)m * 64 + o] = acc[s][r] + b;
        }
    }
}

extern "C" void kernel_launch(void* const* d_in, const int* in_sizes, int n_in,
                              void* d_out, int out_size, void* d_ws, size_t ws_size,
                              hipStream_t stream)
{
    const float* x    = (const float*)d_in[0];
    const int*   ei   = (const int*)d_in[1];
    const float* attr = (const float*)d_in[2];
    const float* W1   = (const float*)d_in[3];
    const float* r1   = (const float*)d_in[4];
    const float* b1   = (const float*)d_in[5];
    const float* W2   = (const float*)d_in[6];
    const float* r2   = (const float*)d_in[7];
    const float* b2   = (const float*)d_in[8];
    const float* fw   = (const float*)d_in[9];
    const float* fb   = (const float*)d_in[10];
    float* out = (float*)d_out;

    const int N = in_sizes[0] / 64;
    const int E = in_sizes[1] / 2;
    const int mtiles = (N + 63) / 64;
    const int Npad = mtiles * 64;

    // workspace carve (~210 MB; ws_size >= 358 MB per round-2 evidence)
    char* p = (char*)d_ws;
    auto alloc = [&](size_t bytes) { void* q = p; p += (bytes + 255) & ~(size_t)255; return q; };
    int4*   epack  = (int4*)alloc((size_t)E * 16);
    ushort* xRoot  = (ushort*)alloc((size_t)Npad * 64 * 2);
    ushort* xWb    = (ushort*)alloc((size_t)Npad * 1600 * 2);
    ushort* xb     = (ushort*)alloc((size_t)Npad * 64 * 2);
    ushort* x1b    = (ushort*)alloc((size_t)Npad * 64 * 2);
    ushort* x2b    = (ushort*)alloc((size_t)Npad * 64 * 2);
    ushort* WtA    = (ushort*)alloc((size_t)26 * 4096 * 2);
    ushort* WtB    = (ushort*)alloc((size_t)26 * 4096 * 2);
    ushort* fwT    = (ushort*)alloc((size_t)3 * 4096 * 2);
    int*    deg    = (int*)alloc((size_t)N * 4);
    int*    cursor = (int*)alloc((size_t)N * 4);
    int*    rowp   = (int*)alloc((size_t)(N + 1) * 4);
    int*    tmpinc = (int*)alloc((size_t)N * 4);
    int*    part   = (int*)alloc(64 * 4);

    const int nb = (N + 1023) / 1024;   // <= 64 for N <= 65536

    // zero deg, then fused prep (xb, WtA, WtB, fwT, hist into deg)
    hipMemsetAsync(deg, 0, (size_t)N * 4, stream);
    const int nx8 = N * 8;              // N*64 elems / 8 per thread
    const int nprep = nx8 + 2 * 26 * 4096 + 3 * 4096 + E;
    prep<<<(nprep + 255) / 256, 256, 0, stream>>>(
        x, xb, nx8, W1, r1, WtA, W2, r2, WtB, fw, fwT, ei, deg, E);

    // CSR scan chain (scatter fused into layer-1 gemm)
    scan_block<<<nb, 1024, 0, stream>>>(deg, tmpinc, part, N);
    scan_partial<<<1, 64, 0, stream>>>(part, nb);
    scan_finalize<<<nb, 1024, 0, stream>>>(deg, tmpinc, part, rowp, cursor, N);

    const int gy = (mtiles + 7) / 8;
    const int sc_blocks = (E + 255) / 256;
    const int sc_cols = (sc_blocks + gy - 1) / gy;

    // layer 1: gemm + scatter fused
    gemm_scatter<<<dim3(26 + sc_cols, gy), 256, 0, stream>>>(
        xb, WtA, xWb, xRoot, mtiles, ei, attr, cursor, epack, E);
    edge_csr<<<(N + 7) / 8, 256, 0, stream>>>(xWb, rowp, epack, xRoot, b1, x1b, N);

    // layer 2: gemm only
    gemm_scatter<<<dim3(26, gy), 256, 0, stream>>>(
        x1b, WtB, xWb, xRoot, mtiles, nullptr, nullptr, nullptr, nullptr, E);
    edge_csr<<<(N + 7) / 8, 256, 0, stream>>>(xWb, rowp, epack, xRoot, b2, x2b, N);

    // final: bf16 MFMA, fp32 out + fb
    final_mfma<<<mtiles, 256, 0, stream>>>(xb, x1b, x2b, fwT, fb, out, N);
}

// Round 10
// 379.713 us; speedup vs baseline: 1.0110x; 1.0110x over previous
//
#include <hip/hip_runtime.h>
#include <hip/hip_bf16.h>

// SplineCNN round 25: re-bank round-23 verbatim (380.5us, session best).
// r24 (2-dst edge + prep-fused hist) was +3.4us: edge VGPR=36 shows the
// compiler serialized the dual quad streams -> no MLP gain; bundle reverted.
// Audit at this state: gemm 70us @3.6TB/s (write-drain ceiling, zero LDS
// conflicts in staging), edge <69.6us @3.2TB/s (random-128B gather
// ceiling), FETCH/WRITE at compulsory levels +-15%. If this reproduces,
// both dominant kernels are at pattern ceilings -> roofline.

typedef short  bf16x8 __attribute__((ext_vector_type(8)));
typedef float  f32x4  __attribute__((ext_vector_type(4)));
typedef int    i32x4  __attribute__((ext_vector_type(4)));
typedef ushort u16x8  __attribute__((ext_vector_type(8)));

__device__ __forceinline__ float bf2f(ushort u) {
    return __uint_as_float((uint)u << 16);
}
__device__ __forceinline__ ushort f2bf(float f) {   // round-to-nearest-even
    uint u = __float_as_uint(f);
    return (ushort)((u + 0x7FFF + ((u >> 16) & 1)) >> 16);
}

// ---------------- fused prep --------------------------------------------
// [0, nx8): xb = bf16(x), 8 elems/thread (vectorized)
// [+nw): WtA[tile][o][i] from W1|r1 ; [+nw): WtB ; [+nfw): fwT ; [+N): deg=0
__global__ __launch_bounds__(256) void prep(
    const float* __restrict__ x, ushort* __restrict__ xb, int nx8,
    const float* __restrict__ W1, const float* __restrict__ r1, ushort* __restrict__ WtA,
    const float* __restrict__ W2, const float* __restrict__ r2, ushort* __restrict__ WtB,
    const float* __restrict__ fw, ushort* __restrict__ fwT,
    int* __restrict__ deg, int N)
{
    const int nw = 26 * 4096, nfw = 3 * 4096;
    int idx = blockIdx.x * 256 + threadIdx.x;
    if (idx < nx8) {
        float4 v0 = *(const float4*)(x + (size_t)idx * 8);
        float4 v1 = *(const float4*)(x + (size_t)idx * 8 + 4);
        u16x8 o;
        o[0] = f2bf(v0.x); o[1] = f2bf(v0.y); o[2] = f2bf(v0.z); o[3] = f2bf(v0.w);
        o[4] = f2bf(v1.x); o[5] = f2bf(v1.y); o[6] = f2bf(v1.z); o[7] = f2bf(v1.w);
        *(u16x8*)(xb + (size_t)idx * 8) = o;
        return;
    }
    idx -= nx8;
    if (idx < nw) {
        int tile = idx >> 12, rem = idx & 4095, o = rem >> 6, i = rem & 63;
        WtA[idx] = f2bf(tile < 25 ? W1[tile * 4096 + i * 64 + o] : r1[i * 64 + o]);
        return;
    }
    idx -= nw;
    if (idx < nw) {
        int tile = idx >> 12, rem = idx & 4095, o = rem >> 6, i = rem & 63;
        WtB[idx] = f2bf(tile < 25 ? W2[tile * 4096 + i * 64 + o] : r2[i * 64 + o]);
        return;
    }
    idx -= nw;
    if (idx < nfw) {
        int t = idx >> 12, rem = idx & 4095, o = rem >> 6, k = rem & 63;
        fwT[idx] = f2bf(fw[(t * 64 + k) * 64 + o]);
        return;
    }
    idx -= nfw;
    if (idx < N) deg[idx] = 0;
}

// ---------------- CSR build ---------------------------------------------
__global__ __launch_bounds__(256) void hist_deg(
    const int* __restrict__ ei, int* __restrict__ deg, int E)
{
    int e = blockIdx.x * 256 + threadIdx.x;
    if (e < E) atomicAdd(&deg[ei[E + e]], 1);
}

__global__ __launch_bounds__(1024) void scan_block(
    const int* __restrict__ deg, int* __restrict__ inc,
    int* __restrict__ partial, int N)
{
    __shared__ int s[1024];
    int i = blockIdx.x * 1024 + threadIdx.x;
    int v = (i < N) ? deg[i] : 0;
    s[threadIdx.x] = v;
    __syncthreads();
    for (int off = 1; off < 1024; off <<= 1) {
        int t = (threadIdx.x >= off) ? s[threadIdx.x - off] : 0;
        __syncthreads();
        s[threadIdx.x] += t;
        __syncthreads();
    }
    if (i < N) inc[i] = s[threadIdx.x];
    if (threadIdx.x == 1023) partial[blockIdx.x] = s[1023];
}

__global__ void scan_partial(int* __restrict__ partial, int nb)  // nb <= 64
{
    __shared__ int s[64];
    int t = threadIdx.x;
    int v = (t < nb) ? partial[t] : 0;
    s[t] = v;
    __syncthreads();
    for (int off = 1; off < 64; off <<= 1) {
        int x = (t >= off) ? s[t - off] : 0;
        __syncthreads();
        s[t] += x;
        __syncthreads();
    }
    if (t < nb) partial[t] = s[t] - v;   // exclusive block offsets
}

__global__ __launch_bounds__(1024) void scan_finalize(
    const int* __restrict__ deg, const int* __restrict__ inc,
    const int* __restrict__ partial, int* __restrict__ row_ptr,
    int* __restrict__ cursor, int N)
{
    int i = blockIdx.x * 1024 + threadIdx.x;
    if (i >= N) return;
    int v = inc[i] + partial[blockIdx.x];
    row_ptr[i + 1] = v;
    cursor[i] = v - deg[i];
    if (i == 0) row_ptr[0] = 0;
}

// ---------------- fused MFMA GEMM + csr_scatter (barrier-free) ----------
__global__ __launch_bounds__(256) void gemm_scatter(
    const ushort* __restrict__ A, const ushort* __restrict__ Wt,
    ushort* __restrict__ xWb, ushort* __restrict__ xRoot, int mtiles,
    const int* __restrict__ ei, const float* __restrict__ attr,
    int* __restrict__ cursor, int4* __restrict__ epack, int E)
{
    __shared__ ushort Cs[4][16][72];   // per-wave slice, 144B rows
    const int bx = blockIdx.x;

    if (bx >= 26) {                 // ---- scatter path (layer 1 only) ----
        if (!ei) return;
        int e = ((bx - 26) * gridDim.y + blockIdx.y) * 256 + threadIdx.x;
        if (e >= E) return;
        int src = ei[e], dst = ei[E + e];
        float u = attr[2 * e] * 4.f;
        float v = attr[2 * e + 1] * 4.f;
        float lu = floorf(u), lv = floorf(v);
        float fu = u - lu, fv = v - lv;
        int iu = (int)lu;  iu = iu < 0 ? 0 : (iu > 4 ? 4 : iu);
        int iv = (int)lv;  iv = iv < 0 ? 0 : (iv > 4 ? 4 : iv);
        int iu1 = iu + 1 > 4 ? 4 : iu + 1;
        int iv1 = iv + 1 > 4 ? 4 : iv + 1;
        uint slots = (uint)(iu + 5 * iv) | ((uint)(iu + 5 * iv1) << 8) |
                     ((uint)(iu1 + 5 * iv) << 16) | ((uint)(iu1 + 5 * iv1) << 24);
        uint wlo = (uint)f2bf((1.f - fu) * (1.f - fv)) | ((uint)f2bf((1.f - fu) * fv) << 16);
        uint whi = (uint)f2bf(fu * (1.f - fv)) | ((uint)f2bf(fu * fv) << 16);
        int pos = atomicAdd(&cursor[dst], 1);
        i32x4 pk = {src * 3200, (int)slots, (int)wlo, (int)whi};
        __builtin_nontemporal_store(pk, (i32x4*)(epack + pos));   // nt: no write-allocate RMW
        return;
    }

    // ---- gemm path ----
    const int wave = threadIdx.x >> 6;
    const int lane = threadIdx.x & 63;
    const int l16 = lane & 15;
    const int half = lane >> 4;                 // 0..3
    ushort (*cw)[72] = Cs[wave];

    const ushort* btile = Wt + (size_t)bx * 4096;
    bf16x8 b0[4], b1[4];
    #pragma unroll
    for (int s = 0; s < 4; ++s) {
        const ushort* brow = btile + (size_t)(s * 16 + l16) * 64;
        b0[s] = *(const bf16x8*)(brow + half * 8);
        b1[s] = *(const bf16x8*)(brow + 32 + half * 8);
    }

    const int mt_base = blockIdx.y * 8;
    const int nit = (mtiles - mt_base) < 8 ? (mtiles - mt_base) : 8;

    // prefetch A for it=0
    const ushort* arow0 = A + (size_t)(mt_base * 64 + wave * 16 + l16) * 64;
    bf16x8 a0 = *(const bf16x8*)(arow0 + half * 8);
    bf16x8 a1 = *(const bf16x8*)(arow0 + 32 + half * 8);

    for (int it = 0; it < nit; ++it) {
        const int m0 = (mt_base + it) * 64;
        const int m_base = m0 + wave * 16;

        // issue next iteration's A loads BEFORE this iteration's stores
        bf16x8 na0, na1;
        if (it + 1 < nit) {
            const ushort* arow = A + (size_t)(m_base + 64 + l16) * 64;
            na0 = *(const bf16x8*)(arow + half * 8);
            na1 = *(const bf16x8*)(arow + 32 + half * 8);
        }

        f32x4 acc[4];
        #pragma unroll
        for (int s = 0; s < 4; ++s) {
            acc[s] = (f32x4){0.f, 0.f, 0.f, 0.f};
            acc[s] = __builtin_amdgcn_mfma_f32_16x16x32_bf16(a0, b0[s], acc[s], 0, 0, 0);
            acc[s] = __builtin_amdgcn_mfma_f32_16x16x32_bf16(a1, b1[s], acc[s], 0, 0, 0);
        }

        if (bx == 25) {   // root tile -> bf16 xRoot (padded ws, no guard)
            #pragma unroll
            for (int s = 0; s < 4; ++s)
                #pragma unroll
                for (int r = 0; r < 4; ++r)
                    xRoot[(size_t)(m_base + half * 4 + r) * 64 + s * 16 + l16] = f2bf(acc[s][r]);
        } else {
            // per-wave stage: bf16 fragment -> LDS slice (same-wave only)
            #pragma unroll
            for (int s = 0; s < 4; ++s)
                #pragma unroll
                for (int r = 0; r < 4; ++r)
                    cw[half * 4 + r][s * 16 + l16] = f2bf(acc[s][r]);
            // same-wave readback -> coalesced uint4 stores of our 16 rows
            #pragma unroll
            for (int i2 = 0; i2 < 2; ++i2) {
                int idx = i2 * 64 + lane;
                int row = idx >> 3, seg = idx & 7;
                uint4 v = *(const uint4*)&cw[row][seg * 8];
                *(uint4*)(xWb + (size_t)(m_base + row) * 1600 + bx * 64 + seg * 8) = v;
            }
        }
        a0 = na0; a1 = na1;
    }
}

// ---------------- edge pass: wave/dst, 4-deep pipelined gather stream ---
__device__ __forceinline__ void gather4(
    const char* __restrict__ xwb, int lane, int rb, uint slots, ushort g[4])
{
    g[0] = *((const ushort*)(xwb + rb + ((slots & 255u) << 7)) + lane);
    g[1] = *((const ushort*)(xwb + rb + (((slots >> 8) & 255u) << 7)) + lane);
    g[2] = *((const ushort*)(xwb + rb + (((slots >> 16) & 255u) << 7)) + lane);
    g[3] = *((const ushort*)(xwb + rb + ((slots >> 24) << 7)) + lane);
}

__device__ __forceinline__ float consume4(const int4 d, const ushort g[4])
{
    float m = __uint_as_float((uint)d.z << 16) * bf2f(g[0]);
    m = fmaf(__uint_as_float((uint)d.z & 0xffff0000u), bf2f(g[1]), m);
    m = fmaf(__uint_as_float((uint)d.w << 16), bf2f(g[2]), m);
    m = fmaf(__uint_as_float((uint)d.w & 0xffff0000u), bf2f(g[3]), m);
    return m;
}

__global__ __launch_bounds__(256) void edge_csr(
    const ushort* __restrict__ xWb, const int* __restrict__ row_ptr,
    const int4* __restrict__ epack, const ushort* __restrict__ xRoot,
    const float* __restrict__ bias, float* __restrict__ outf,
    ushort* __restrict__ outb, int N)
{
    const int wv = __builtin_amdgcn_readfirstlane(threadIdx.x >> 6);
    const int d = blockIdx.x * 4 + wv;
    const int lane = threadIdx.x & 63;
    if (d >= N) return;
    const int e0 = __builtin_amdgcn_readfirstlane(row_ptr[d]);
    const int e1 = __builtin_amdgcn_readfirstlane(row_ptr[d + 1]);
    const char* xwb = (const char*)xWb;
    const int cnt = e1 - e0;

    float vmax = -__builtin_inff();
    int e = e0;
    const int quads = cnt >> 2;
    if (quads > 0) {
        int4 dq[4]; ushort gq[4][4];
        #pragma unroll
        for (int j = 0; j < 4; ++j) {
            dq[j] = epack[e + j];
            gather4(xwb, lane, dq[j].x, (uint)dq[j].y, gq[j]);
        }
        for (int q = 1; q < quads; ++q) {
            int4 nd[4]; ushort ng[4][4];
            #pragma unroll
            for (int j = 0; j < 4; ++j) {
                nd[j] = epack[e + 4 * q + j];
                gather4(xwb, lane, nd[j].x, (uint)nd[j].y, ng[j]);
            }
            #pragma unroll
            for (int j = 0; j < 4; ++j)
                vmax = fmaxf(vmax, consume4(dq[j], gq[j]));
            #pragma unroll
            for (int j = 0; j < 4; ++j) {
                dq[j] = nd[j];
                #pragma unroll
                for (int i = 0; i < 4; ++i) gq[j][i] = ng[j][i];
            }
        }
        #pragma unroll
        for (int j = 0; j < 4; ++j)
            vmax = fmaxf(vmax, consume4(dq[j], gq[j]));
        e += quads * 4;
    }
    for (; e < e1; ++e) {   // remainder (<=3)
        int4 dA = epack[e];
        ushort gA[4];
        gather4(xwb, lane, dA.x, (uint)dA.y, gA);
        vmax = fmaxf(vmax, consume4(dA, gA));
    }
    if (cnt == 0) vmax = 0.f;          // segment_max(-inf) -> 0
    float val = vmax + bf2f(xRoot[(size_t)d * 64 + lane]) + bias[lane];
    val = fmaxf(val, 0.f);
    if (outf) outf[(size_t)d * 64 + lane] = val;
    if (outb) outb[(size_t)d * 64 + lane] = f2bf(val);
}

// ---------------- final: out = [xb|x1b|x2b] @ fwT + fb (bf16 MFMA) ------
__global__ __launch_bounds__(256) void final_mfma(
    const ushort* __restrict__ xb, const ushort* __restrict__ x1b,
    const ushort* __restrict__ x2b, const ushort* __restrict__ fwT,
    const float* __restrict__ fb, float* __restrict__ out, int M)
{
    const int wave = threadIdx.x >> 6;
    const int lane = threadIdx.x & 63;
    const int l16 = lane & 15;
    const int half = lane >> 4;
    const int m_base = blockIdx.x * 64 + wave * 16;
    const ushort* srcs[3] = {xb, x1b, x2b};

    f32x4 acc[4];
    #pragma unroll
    for (int s = 0; s < 4; ++s) acc[s] = (f32x4){0.f, 0.f, 0.f, 0.f};

    #pragma unroll
    for (int t = 0; t < 3; ++t) {
        const ushort* arow = srcs[t] + (size_t)(m_base + l16) * 64;
        bf16x8 a0 = *(const bf16x8*)(arow + half * 8);
        bf16x8 a1 = *(const bf16x8*)(arow + 32 + half * 8);
        const ushort* btile = fwT + (size_t)t * 4096;
        #pragma unroll
        for (int s = 0; s < 4; ++s) {
            const ushort* brow = btile + (size_t)(s * 16 + l16) * 64;
            bf16x8 b0 = *(const bf16x8*)(brow + half * 8);
            bf16x8 b1 = *(const bf16x8*)(brow + 32 + half * 8);
            acc[s] = __builtin_amdgcn_mfma_f32_16x16x32_bf16(a0, b0, acc[s], 0, 0, 0);
            acc[s] = __builtin_amdgcn_mfma_f32_16x16x32_bf16(a1, b1, acc[s], 0, 0, 0);
        }
    }

    #pragma unroll
    for (int s = 0; s < 4; ++s) {
        int o = s * 16 + l16;
        float b = fb[o];
        #pragma unroll
        for (int r = 0; r < 4; ++r) {
            int m = m_base + half * 4 + r;
            if (m < M) out[(size_t)m * 64 + o] = acc[s][r] + b;
        }
    }
}

extern "C" void kernel_launch(void* const* d_in, const int* in_sizes, int n_in,
                              void* d_out, int out_size, void* d_ws, size_t ws_size,
                              hipStream_t stream)
{
    const float* x    = (const float*)d_in[0];
    const int*   ei   = (const int*)d_in[1];
    const float* attr = (const float*)d_in[2];
    const float* W1   = (const float*)d_in[3];
    const float* r1   = (const float*)d_in[4];
    const float* b1   = (const float*)d_in[5];
    const float* W2   = (const float*)d_in[6];
    const float* r2   = (const float*)d_in[7];
    const float* b2   = (const float*)d_in[8];
    const float* fw   = (const float*)d_in[9];
    const float* fb   = (const float*)d_in[10];
    float* out = (float*)d_out;

    const int N = in_sizes[0] / 64;
    const int E = in_sizes[1] / 2;
    const int mtiles = (N + 63) / 64;
    const int Npad = mtiles * 64;

    // workspace carve (~210 MB; ws_size >= 358 MB per round-2 evidence)
    char* p = (char*)d_ws;
    auto alloc = [&](size_t bytes) { void* q = p; p += (bytes + 255) & ~(size_t)255; return q; };
    int4*   epack  = (int4*)alloc((size_t)E * 16);
    ushort* xRoot  = (ushort*)alloc((size_t)Npad * 64 * 2);
    ushort* xWb    = (ushort*)alloc((size_t)Npad * 1600 * 2);
    ushort* xb     = (ushort*)alloc((size_t)Npad * 64 * 2);
    ushort* x1b    = (ushort*)alloc((size_t)Npad * 64 * 2);
    ushort* x2b    = (ushort*)alloc((size_t)Npad * 64 * 2);
    ushort* WtA    = (ushort*)alloc((size_t)26 * 4096 * 2);
    ushort* WtB    = (ushort*)alloc((size_t)26 * 4096 * 2);
    ushort* fwT    = (ushort*)alloc((size_t)3 * 4096 * 2);
    int*    deg    = (int*)alloc((size_t)N * 4);
    int*    cursor = (int*)alloc((size_t)N * 4);
    int*    rowp   = (int*)alloc((size_t)(N + 1) * 4);
    int*    tmpinc = (int*)alloc((size_t)N * 4);
    int*    part   = (int*)alloc(64 * 4);

    const int nb = (N + 1023) / 1024;   // <= 64 for N <= 65536

    // fused prep: xb (vectorized x8), WtA, WtB, fwT, zero deg
    const int nx8 = N * 8;              // N*64 elems / 8 per thread
    const int nprep = nx8 + 2 * 26 * 4096 + 3 * 4096 + N;
    prep<<<(nprep + 255) / 256, 256, 0, stream>>>(
        x, xb, nx8, W1, r1, WtA, W2, r2, WtB, fw, fwT, deg, N);

    // CSR scan chain (scatter fused into layer-1 gemm)
    hist_deg<<<(E + 255) / 256, 256, 0, stream>>>(ei, deg, E);
    scan_block<<<nb, 1024, 0, stream>>>(deg, tmpinc, part, N);
    scan_partial<<<1, 64, 0, stream>>>(part, nb);
    scan_finalize<<<nb, 1024, 0, stream>>>(deg, tmpinc, part, rowp, cursor, N);

    const int gy = (mtiles + 7) / 8;
    const int sc_blocks = (E + 255) / 256;
    const int sc_cols = (sc_blocks + gy - 1) / gy;

    // layer 1: gemm + scatter fused
    gemm_scatter<<<dim3(26 + sc_cols, gy), 256, 0, stream>>>(
        xb, WtA, xWb, xRoot, mtiles, ei, attr, cursor, epack, E);
    edge_csr<<<(N + 3) / 4, 256, 0, stream>>>(xWb, rowp, epack, xRoot, b1, nullptr, x1b, N);

    // layer 2: gemm only
    gemm_scatter<<<dim3(26, gy), 256, 0, stream>>>(
        x1b, WtB, xWb, xRoot, mtiles, nullptr, nullptr, nullptr, nullptr, E);
    edge_csr<<<(N + 3) / 4, 256, 0, stream>>>(xWb, rowp, epack, xRoot, b2, nullptr, x2b, N);

    // final: bf16 MFMA, fp32 out + fb
    final_mfma<<<mtiles, 256, 0, stream>>>(xb, x1b, x2b, fwT, fb, out, N);
}